// Round 4
// 22564.757 us; speedup vs baseline: 1.8537x; 1.8537x over previous
//
#include <hip/hip_runtime.h>

#define NB 64
#define NT 256
#define NF 512
#define NU 1024
#define NWG 256
#define NTHR 256
#define SLICE 65536   // 64*1024 floats per partial K-slice

typedef float f32x4 __attribute__((ext_vector_type(4)));

__device__ __forceinline__ float sigm(float x) { return 1.f / (1.f + __expf(-x)); }

// ---- memory ops -------------------------------------------------------------
// Protocol (round-3 post-mortem):
//  * producers write cross-WG data with PLAIN stores (dirty in local L2), and
//    release via __builtin_amdgcn_fence(RELEASE, "agent") = buffer_wbl2 +
//    waitcnt. wbl2 flushes DIRTY lines only -> clean weights stay L2-resident.
//  * consumers read cross-WG data with sc0 sc1 scoped loads (bypass stale
//    L1/L2, read the coherence point). No buffer_inv anywhere -> weights are
//    never evicted. Scoped loads observing remote stores is proven by the
//    flag-polling protocol itself (worked fence-free in rounds 2/3).
// Inline-asm loads are NOT dependency-tracked: component reads only after
// vm_wait().
__device__ __forceinline__ f32x4 ld_cg4(const float* p) {
  f32x4 t;
  asm volatile("global_load_dwordx4 %0, %1, off sc0 sc1" : "=&v"(t) : "v"(p));
  return t;
}
__device__ __forceinline__ float ld_cg1(const float* p) {
  float t;
  asm volatile("global_load_dword %0, %1, off sc0 sc1" : "=&v"(t) : "v"(p));
  return t;
}
__device__ __forceinline__ f32x4 ld_nc4(const float* p) {  // cached load (weights/x)
  f32x4 t;
  asm volatile("global_load_dwordx4 %0, %1, off" : "=&v"(t) : "v"(p));
  return t;
}
__device__ __forceinline__ void vm_wait() {
  asm volatile("s_waitcnt vmcnt(0)" ::: "memory");
  __builtin_amdgcn_sched_barrier(0);
}

struct KParams {
  const float *x, *g1, *b1, *g2, *b2;
  const float *Wx, *Wh, *Wf, *Wi, *Wq, *Wk, *Wv, *Wo;
  float *out;
  float *xxp, *fip, *qkvp, *wop;           // K-split partial slices
  float *xxm, *lt, *sp, *c, *attb, *stats; // stats: [0..63]=sp mean [64..]=sp rstd [128..]=lt mean [192..]=lt rstd
  int *flags, *grel;
};

// ---- grid barrier: producer-release (wbl2, dirty-only) + scoped-load acquire ----
// dirty = this WG wrote cross-WG data this phase (skip wbl2 walk otherwise).
__device__ __forceinline__ void grid_barrier(int* flags, int* grel, int epoch,
                                             int wg, int tid, bool dirty) {
  asm volatile("s_waitcnt vmcnt(0) lgkmcnt(0)" ::: "memory");
  __syncthreads();   // all waves' plain stores are in L2 before tid0's wbl2
  if (wg == 0) {
    if (tid > 0) {   // thread i polls WG i's private arrival line
      while (__hip_atomic_load(&flags[tid * 16], __ATOMIC_RELAXED, __HIP_MEMORY_SCOPE_AGENT) < epoch)
        __builtin_amdgcn_s_sleep(1);
    }
    __syncthreads();
    if (tid == 0)
      __builtin_amdgcn_fence(__ATOMIC_RELEASE, "agent");  // wbl2+waitcnt, NO inv
    __syncthreads();
    if (tid < 16)    // hierarchical release: 16 group lines
      __hip_atomic_store(&grel[tid * 16], epoch, __ATOMIC_RELAXED, __HIP_MEMORY_SCOPE_AGENT);
    __syncthreads();
  } else {
    if (tid == 0) {
      if (dirty)
        __builtin_amdgcn_fence(__ATOMIC_RELEASE, "agent");  // flush own XCD's dirty lines
      __hip_atomic_store(&flags[wg * 16], epoch, __ATOMIC_RELAXED, __HIP_MEMORY_SCOPE_AGENT);
      const int g = wg >> 4;
      while (__hip_atomic_load(&grel[g * 16], __ATOMIC_RELAXED, __HIP_MEMORY_SCOPE_AGENT) < epoch)
        __builtin_amdgcn_s_sleep(1);
    }
    __syncthreads();
  }
}

// ---- one 64x64 output tile over K = nchunks*64, LDS-staged A and W ----
// A-stage modes: 0 = direct rows, cached (x)      4 = direct rows, scoped (attb)
//                1 = h on-the-fly (LN1(sp)+sum4(wop), optional out write)
//                2 = sum 6 xx partials (optional xxm write)   3 = LN1(sp)
__device__ __forceinline__ void gemm_tile(
    float* As, float* Wl, const float* smm, const float* smr,
    int mode, const float* A0, size_t a_ld,
    const float* g1, const float* b1, const float* wop,
    float* outw, size_t out_ld,
    const float* __restrict__ W, int n0, int k0, int nchunks,
    float* __restrict__ dst, int tid)
{
  const int cg = tid & 15, rg = tid >> 4;
  const int c0 = cg * 4, r0 = rg * 4;
  float4 acc0 = {0,0,0,0}, acc1 = {0,0,0,0}, acc2 = {0,0,0,0}, acc3 = {0,0,0,0};

  for (int cc = 0; cc < nchunks; ++cc) {
    const int kc = k0 + cc * 64;
    __syncthreads();

    // ---- issue W tile loads (cached: weights are read-only, stay L2-hot) ----
    f32x4 wv[4];
#pragma unroll
    for (int it = 0; it < 4; ++it) {
      int idx = tid + it * 256;
      int kk = idx >> 4, cgs = idx & 15;
      wv[it] = ld_nc4(W + (size_t)(kc + kk) * NU + n0 + cgs * 4);
    }

    // ---- A tile (raw f32x4; components only touched after a vm_wait) ----
    f32x4 v[4];
    if (mode == 0) {
#pragma unroll
      for (int it = 0; it < 4; ++it) {
        int idx = tid + it * 256;
        int r = idx >> 4, k4 = (idx & 15) << 2;
        v[it] = ld_nc4(A0 + (size_t)r * a_ld + kc + k4);
      }
    } else if (mode == 4) {
#pragma unroll
      for (int it = 0; it < 4; ++it) {
        int idx = tid + it * 256;
        int r = idx >> 4, k4 = (idx & 15) << 2;
        v[it] = ld_cg4(A0 + (size_t)r * a_ld + kc + k4);
      }
    } else if (mode == 3) {
      f32x4 av[4];
#pragma unroll
      for (int it = 0; it < 4; ++it) {
        int idx = tid + it * 256;
        int r = idx >> 4, k4 = (idx & 15) << 2;
        av[it] = ld_cg4(A0 + (size_t)r * NU + kc + k4);
      }
      vm_wait();
#pragma unroll
      for (int it = 0; it < 4; ++it) {
        int idx = tid + it * 256;
        int r = idx >> 4, k4 = (idx & 15) << 2;
        int col = kc + k4;
        float m = smm[r], rs = smr[r];
        f32x4 g  = *(const f32x4*)(g1 + col);
        f32x4 be = *(const f32x4*)(b1 + col);
        v[it] = (av[it] - m) * rs * g + be;
      }
    } else if (mode == 1) {
      if (A0) {
        f32x4 sv[4], w0v[4], w1v[4];
#pragma unroll
        for (int it = 0; it < 4; ++it) {
          int idx = tid + it * 256;
          int r = idx >> 4, k4 = (idx & 15) << 2;
          int col = kc + k4;
          sv[it]  = ld_cg4(A0 + (size_t)r * NU + col);
          w0v[it] = ld_cg4(wop + 0 * SLICE + (size_t)r * NU + col);
          w1v[it] = ld_cg4(wop + 1 * SLICE + (size_t)r * NU + col);
        }
        vm_wait();
        f32x4 pp[4];
#pragma unroll
        for (int it = 0; it < 4; ++it) {
          int idx = tid + it * 256;
          int r = idx >> 4, k4 = (idx & 15) << 2;
          int col = kc + k4;
          float m = smm[r], rs = smr[r];
          f32x4 g  = *(const f32x4*)(g1 + col);
          f32x4 be = *(const f32x4*)(b1 + col);
          pp[it] = (sv[it] - m) * rs * g + be + w0v[it] + w1v[it];
        }
#pragma unroll
        for (int it = 0; it < 4; ++it) {
          int idx = tid + it * 256;
          int r = idx >> 4, k4 = (idx & 15) << 2;
          int col = kc + k4;
          w0v[it] = ld_cg4(wop + 2 * SLICE + (size_t)r * NU + col);
          w1v[it] = ld_cg4(wop + 3 * SLICE + (size_t)r * NU + col);
        }
        vm_wait();
#pragma unroll
        for (int it = 0; it < 4; ++it) {
          int idx = tid + it * 256;
          int r = idx >> 4, k4 = (idx & 15) << 2;
          v[it] = pp[it] + w0v[it] + w1v[it];
          if (outw) *(f32x4*)(outw + (size_t)r * out_ld + kc + k4) = v[it];  // plain store
        }
      } else {
#pragma unroll
        for (int it = 0; it < 4; ++it) v[it] = (f32x4){0.f, 0.f, 0.f, 0.f};
      }
    } else {  // mode 2: sum 6 xx partial slices
      f32x4 s0[4], s1[4], s2[4];
#pragma unroll
      for (int it = 0; it < 4; ++it) {
        int idx = tid + it * 256;
        int r = idx >> 4, k4 = (idx & 15) << 2;
        const float* bp = A0 + (size_t)r * NU + kc + k4;
        s0[it] = ld_cg4(bp);
        s1[it] = ld_cg4(bp + SLICE);
        s2[it] = ld_cg4(bp + 2 * SLICE);
      }
      vm_wait();
      f32x4 pp[4];
#pragma unroll
      for (int it = 0; it < 4; ++it) pp[it] = s0[it] + s1[it] + s2[it];
#pragma unroll
      for (int it = 0; it < 4; ++it) {
        int idx = tid + it * 256;
        int r = idx >> 4, k4 = (idx & 15) << 2;
        const float* bp = A0 + 3 * SLICE + (size_t)r * NU + kc + k4;
        s0[it] = ld_cg4(bp);
        s1[it] = ld_cg4(bp + SLICE);
        s2[it] = ld_cg4(bp + 2 * SLICE);
      }
      vm_wait();
#pragma unroll
      for (int it = 0; it < 4; ++it) {
        int idx = tid + it * 256;
        int r = idx >> 4, k4 = (idx & 15) << 2;
        v[it] = pp[it] + s0[it] + s1[it] + s2[it];
        if (outw) *(f32x4*)(outw + (size_t)r * NU + kc + k4) = v[it];  // xxm, plain store
      }
    }

    vm_wait();   // drains wv (and mode-0/4 v); ONLY NOW may their components be read
#pragma unroll
    for (int it = 0; it < 4; ++it) {
      int idx = tid + it * 256;
      int r = idx >> 4, k4 = (idx & 15) << 2;
      *(f32x4*)(&As[r * 68 + k4]) = v[it];
    }
#pragma unroll
    for (int it = 0; it < 4; ++it) {
      int idx = tid + it * 256;
      int kk = idx >> 4, cgs = idx & 15;
      int sw = (((kk >> 2) ^ cgs) & 15) << 2;
      int base = (cgs * 4) * 68 + sw + (kk & 3);
      Wl[base] = wv[it].x; Wl[base + 68] = wv[it].y; Wl[base + 136] = wv[it].z; Wl[base + 204] = wv[it].w;
    }
    __syncthreads();
    // 4x4 register-tile accumulate (validated r7)
#pragma unroll
    for (int kk = 0; kk < 64; kk += 4) {
      int sw = ((((kk >> 2) ^ cg) & 15) << 2);
      const float4 w0 = *(const float4*)(&Wl[(c0 + 0) * 68 + sw]);
      const float4 w1 = *(const float4*)(&Wl[(c0 + 1) * 68 + sw]);
      const float4 w2 = *(const float4*)(&Wl[(c0 + 2) * 68 + sw]);
      const float4 w3 = *(const float4*)(&Wl[(c0 + 3) * 68 + sw]);
      const float4 a0 = *(const float4*)(&As[(r0 + 0) * 68 + kk]);
      const float4 a1 = *(const float4*)(&As[(r0 + 1) * 68 + kk]);
      const float4 a2 = *(const float4*)(&As[(r0 + 2) * 68 + kk]);
      const float4 a3 = *(const float4*)(&As[(r0 + 3) * 68 + kk]);
#define DOT4(ac, av) \
      ac.x = fmaf(av.x, w0.x, fmaf(av.y, w0.y, fmaf(av.z, w0.z, fmaf(av.w, w0.w, ac.x)))); \
      ac.y = fmaf(av.x, w1.x, fmaf(av.y, w1.y, fmaf(av.z, w1.z, fmaf(av.w, w1.w, ac.y)))); \
      ac.z = fmaf(av.x, w2.x, fmaf(av.y, w2.y, fmaf(av.z, w2.z, fmaf(av.w, w2.w, ac.z)))); \
      ac.w = fmaf(av.x, w3.x, fmaf(av.y, w3.y, fmaf(av.z, w3.z, fmaf(av.w, w3.w, ac.w))));
      DOT4(acc0, a0) DOT4(acc1, a1) DOT4(acc2, a2) DOT4(acc3, a3)
#undef DOT4
    }
  }
  // plain coalesced stores; flushed to the coherence point by the barrier's wbl2
  *(float4*)(dst + (size_t)(r0 + 0) * NU + n0 + c0) = acc0;
  *(float4*)(dst + (size_t)(r0 + 1) * NU + n0 + c0) = acc1;
  *(float4*)(dst + (size_t)(r0 + 2) * NU + n0 + c0) = acc2;
  *(float4*)(dst + (size_t)(r0 + 3) * NU + n0 + c0) = acc3;
}

__global__ __launch_bounds__(NTHR, 1) void vecaw_main(KParams p) {
  const int wg = blockIdx.x;
  const int tid = threadIdx.x;

  __shared__ __align__(16) float As[64 * 68];
  __shared__ __align__(16) float Wl[64 * 68];
  __shared__ float smm[64], smr[64], red[16], att_s[64];

  int epoch = 0;

  for (int t = 0; t < NT; ++t) {

    // ===== P1: xx partials (Wh 64 WGs + Wx 32 WGs); h on-the-fly; out(t-1) =====
    if (wg < 64) {
      const int nt = wg & 15, ks = wg >> 4;
      if (tid < 64 && t > 0) {
        float m = ld_cg1(p.stats + tid);
        float r = ld_cg1(p.stats + 64 + tid);
        vm_wait();
        smm[tid] = m; smr[tid] = r;
      }
      float* outw = (nt == 0 && t > 0) ? (p.out + (size_t)(t - 1) * NU) : nullptr;
      gemm_tile(As, Wl, smm, smr, 1, (t > 0) ? p.sp : nullptr, NU,
                p.g1, p.b1, p.wop, outw, (size_t)NT * NU,
                p.Wh, nt * 64, ks * 256, 4, p.xxp + (size_t)ks * SLICE, tid);
    } else if (wg < 96) {
      const int idx = wg - 64, nt = idx & 15, ks = idx >> 4;
      gemm_tile(As, Wl, nullptr, nullptr, 0, p.x + (size_t)t * NF, (size_t)NT * NF,
                nullptr, nullptr, nullptr, nullptr, 0,
                p.Wx, nt * 64, ks * 256, 4, p.xxp + (size_t)(4 + ks) * SLICE, tid);
    }
    grid_barrier(p.flags, p.grel, ++epoch, wg, tid, wg < 96);

    // ===== P2: f,i partials (128 WGs, K=256); materialize xx =====
    if (wg < 128) {
      const int mat = wg >> 6, idx = wg & 63, nt = idx & 15, ks = idx >> 4;
      float* outw = (mat == 0 && nt == 0) ? p.xxm : nullptr;
      gemm_tile(As, Wl, nullptr, nullptr, 2, p.xxp, NU,
                nullptr, nullptr, nullptr, outw, NU,
                mat ? p.Wi : p.Wf, nt * 64, ks * 256, 4,
                p.fip + (size_t)(mat * 4 + ks) * SLICE, tid);
    }
    grid_barrier(p.flags, p.grel, ++epoch, wg, tid, wg < 128);

    // ===== P3: elementwise + per-row LN stats (64 WGs, f32x4/thread, no atomics) =====
    if (wg < 64) {
      const int b = wg;
      const size_t off = (size_t)b * NU + tid * 4;
      f32x4 xq = ld_cg4(p.xxm + off);
      f32x4 f0 = ld_cg4(p.fip + off);
      f32x4 f1 = ld_cg4(p.fip + SLICE + off);
      f32x4 f2 = ld_cg4(p.fip + 2 * SLICE + off);
      f32x4 f3 = ld_cg4(p.fip + 3 * SLICE + off);
      f32x4 i0 = ld_cg4(p.fip + 4 * SLICE + off);
      f32x4 i1 = ld_cg4(p.fip + 5 * SLICE + off);
      f32x4 i2 = ld_cg4(p.fip + 6 * SLICE + off);
      f32x4 i3 = ld_cg4(p.fip + 7 * SLICE + off);
      f32x4 cq = ld_cg4(p.c + off);
      vm_wait();
      f32x4 fsv = f0 + f1 + f2 + f3;
      f32x4 isv = i0 + i1 + i2 + i3;
      f32x4 ltq, spq;
#define P3COMP(C) { \
      float xxv = xq.C; \
      float f = sigm(fsv.C), i = sigm(isv.C); \
      float ltv = f * cq.C + i * tanhf(xxv); \
      float sw = xxv * sigm(xxv); \
      float spin = ltv + sw; \
      ltq.C = ltv; spq.C = spin * sigm(spin); }
      P3COMP(x) P3COMP(y) P3COMP(z) P3COMP(w)
#undef P3COMP
      *(f32x4*)(p.lt + off) = ltq;   // plain stores; wbl2 at barrier flushes
      *(f32x4*)(p.sp + off) = spq;
      float s0 = spq.x + spq.y + spq.z + spq.w;
      float s1 = spq.x*spq.x + spq.y*spq.y + spq.z*spq.z + spq.w*spq.w;
      float s2 = ltq.x + ltq.y + ltq.z + ltq.w;
      float s3 = ltq.x*ltq.x + ltq.y*ltq.y + ltq.z*ltq.z + ltq.w*ltq.w;
#pragma unroll
      for (int m = 1; m < 64; m <<= 1) {
        s0 += __shfl_xor(s0, m, 64); s1 += __shfl_xor(s1, m, 64);
        s2 += __shfl_xor(s2, m, 64); s3 += __shfl_xor(s3, m, 64);
      }
      if ((tid & 63) == 0) {
        int wv = tid >> 6;
        red[wv * 4 + 0] = s0; red[wv * 4 + 1] = s1;
        red[wv * 4 + 2] = s2; red[wv * 4 + 3] = s3;
      }
      __syncthreads();
      if (tid == 0) {
        float S0 = red[0] + red[4] + red[8]  + red[12];
        float S1 = red[1] + red[5] + red[9]  + red[13];
        float S2 = red[2] + red[6] + red[10] + red[14];
        float S3 = red[3] + red[7] + red[11] + red[15];
        float m1 = S0 * (1.f / 1024.f), v1 = S1 * (1.f / 1024.f) - m1 * m1;
        float m2 = S2 * (1.f / 1024.f), v2 = S3 * (1.f / 1024.f) - m2 * m2;
        p.stats[b]       = m1;
        p.stats[64 + b]  = rsqrtf(v1 + 1e-3f);
        p.stats[128 + b] = m2;
        p.stats[192 + b] = rsqrtf(v2 + 1e-3f);
      }
    }
    grid_barrier(p.flags, p.grel, ++epoch, wg, tid, wg < 64);

    // ===== P4: q,k,v partials with LN1-on-stage (192 WGs) + c = LN2(lt) (64 WGs) =====
    if (wg < 192) {
      if (tid < 64) {
        float m = ld_cg1(p.stats + tid);
        float r = ld_cg1(p.stats + 64 + tid);
        vm_wait();
        smm[tid] = m; smr[tid] = r;
      }
      const int mat = wg >> 6, idx = wg & 63, nt = idx & 15, ks = idx >> 4;
      const float* W = (mat == 0) ? p.Wq : (mat == 1) ? p.Wk : p.Wv;
      gemm_tile(As, Wl, smm, smr, 3, p.sp, NU,
                p.g1, p.b1, nullptr, nullptr, 0,
                W, nt * 64, ks * 256, 4, p.qkvp + (size_t)(mat * 4 + ks) * SLICE, tid);
    } else {
      const int b = wg - 192;
      float m  = ld_cg1(p.stats + 128 + b);
      float rv = ld_cg1(p.stats + 192 + b);
      f32x4 l4 = ld_cg4(p.lt + (size_t)b * NU + tid * 4);
      vm_wait();
      f32x4 g  = *(const f32x4*)(p.g2 + tid * 4);
      f32x4 be = *(const f32x4*)(p.b2 + tid * 4);
      f32x4 cv = (l4 - m) * rv * g + be;
      *(f32x4*)(p.c + (size_t)b * NU + tid * 4) = cv;
    }
    grid_barrier(p.flags, p.grel, ++epoch, wg, tid, true);

    // ===== P5a: per-batch 8x8 attention (64 WGs); q,k,v summed from partials =====
    if (wg < 64) {
      const int b = wg;
      f32x4 q0[3], q1[3], q2[3], q3[3];
#pragma unroll
      for (int it = 0; it < 3; ++it) {
        int e4 = (tid + it * 256) * 4;
        int m = e4 >> 10, d = e4 & 1023;
        const float* base = p.qkvp + (size_t)(m * 4) * SLICE + (size_t)b * NU + d;
        q0[it] = ld_cg4(base);
        q1[it] = ld_cg4(base + SLICE);
        q2[it] = ld_cg4(base + 2 * SLICE);
        q3[it] = ld_cg4(base + 3 * SLICE);
      }
      vm_wait();
#pragma unroll
      for (int it = 0; it < 3; ++it) {
        int e4 = (tid + it * 256) * 4;
        f32x4 s = q0[it] + q1[it] + q2[it] + q3[it];
        *(f32x4*)(&As[e4]) = s;
      }
      __syncthreads();
      if (tid < 64) {
        int h = tid >> 3, g = tid & 7;
        float s = 0.f;
#pragma unroll 8
        for (int d = 0; d < 128; ++d) s = fmaf(As[h * 128 + d], As[1024 + g * 128 + d], s);
        att_s[tid] = s * 0.08838834764831845f;   // 1/sqrt(128)
      }
      __syncthreads();
      if (tid < 8) {
        float mx = -1e30f;
#pragma unroll
        for (int g = 0; g < 8; ++g) mx = fmaxf(mx, att_s[tid * 8 + g]);
        float e8[8], sum = 0.f;
#pragma unroll
        for (int g = 0; g < 8; ++g) { e8[g] = __expf(att_s[tid * 8 + g] - mx); sum += e8[g]; }
        float inv = 1.f / sum;
#pragma unroll
        for (int g = 0; g < 8; ++g) att_s[tid * 8 + g] = e8[g] * inv;
      }
      __syncthreads();
      {
        int idx4 = tid * 4;
        int h = idx4 >> 7, d = idx4 & 127;
        f32x4 a = {0.f, 0.f, 0.f, 0.f};
#pragma unroll
        for (int g = 0; g < 8; ++g) {
          float w = att_s[h * 8 + g];
          a += w * (*(const f32x4*)(&As[2048 + g * 128 + d]));
        }
        *(f32x4*)(p.attb + (size_t)b * NU + idx4) = a;
      }
    }
    grid_barrier(p.flags, p.grel, ++epoch, wg, tid, wg < 64);

    // ===== P5b: wo partials (64 WGs, K=256) =====
    if (wg < 64) {
      const int nt = wg & 15, ks = wg >> 4;
      gemm_tile(As, Wl, nullptr, nullptr, 4, p.attb, NU,
                nullptr, nullptr, nullptr, nullptr, 0,
                p.Wo, nt * 64, ks * 256, 4, p.wop + (size_t)ks * SLICE, tid);
    }
    grid_barrier(p.flags, p.grel, ++epoch, wg, tid, wg < 64);
  }

  // ===== final epilogue: out(255) = LN1(sp) + sum(wop) =====
  if (wg < 64) {
    const int b = wg;
    const int u4 = tid * 4;
    const size_t off = (size_t)b * NU + u4;
    float m  = ld_cg1(p.stats + b);
    float rs = ld_cg1(p.stats + 64 + b);
    f32x4 s4 = ld_cg4(p.sp + off);
    f32x4 w0 = ld_cg4(p.wop + off);
    f32x4 w1 = ld_cg4(p.wop + SLICE + off);
    f32x4 w2 = ld_cg4(p.wop + 2 * SLICE + off);
    f32x4 w3 = ld_cg4(p.wop + 3 * SLICE + off);
    vm_wait();
    f32x4 g  = *(const f32x4*)(p.g1 + u4);
    f32x4 be = *(const f32x4*)(p.b1 + u4);
    f32x4 o = (s4 - m) * rs * g + be + w0 + w1 + w2 + w3;
    *(f32x4*)(p.out + ((size_t)b * NT + 255) * NU + u4) = o;
  }
}

extern "C" void kernel_launch(void* const* d_in, const int* in_sizes, int n_in,
                              void* d_out, int out_size, void* d_ws, size_t ws_size,
                              hipStream_t stream) {
  (void)in_sizes; (void)n_in; (void)out_size; (void)ws_size;
  const float* x  = (const float*)d_in[0];
  const float* Wx = (const float*)d_in[1];
  const float* Wh = (const float*)d_in[2];
  const float* Wq = (const float*)d_in[3];
  const float* Wk = (const float*)d_in[4];
  const float* Wv = (const float*)d_in[5];
  const float* Wo = (const float*)d_in[6];
  const float* Wf = (const float*)d_in[7];
  const float* Wi = (const float*)d_in[8];
  const float* g1 = (const float*)d_in[9];
  const float* b1 = (const float*)d_in[10];
  const float* g2 = (const float*)d_in[11];
  const float* b2 = (const float*)d_in[12];

  char* pp = (char*)d_ws;
  auto take = [&](size_t bytes) { char* r = pp; pp += (bytes + 255) & ~(size_t)255; return r; };
  // --- memset region: flags | grel | stats | c ---
  int*   flags = (int*)take(256 * 16 * 4);     // one 64B line per WG
  int*   grel  = (int*)take(16 * 16 * 4);      // one 64B line per 16-WG group
  float* stats = (float*)take(2 * 256 * 4);    // [mean_sp|rstd_sp|mean_lt|rstd_lt] x 64
  float* c     = (float*)take((size_t)SLICE * 4);
  size_t zbytes = (size_t)(pp - (char*)d_ws);
  // --- rest (fully overwritten each step before read) ---
  float* xxp   = (float*)take((size_t)6 * SLICE * 4);
  float* fip   = (float*)take((size_t)8 * SLICE * 4);
  float* qkvp  = (float*)take((size_t)12 * SLICE * 4);
  float* wop   = (float*)take((size_t)4 * SLICE * 4);
  float* xxm   = (float*)take((size_t)SLICE * 4);
  float* lt    = (float*)take((size_t)SLICE * 4);
  float* sp    = (float*)take((size_t)SLICE * 4);
  float* attb  = (float*)take((size_t)SLICE * 4);

  hipMemsetAsync(d_ws, 0, zbytes, stream);

  KParams kp;
  kp.x = x; kp.g1 = g1; kp.b1 = b1; kp.g2 = g2; kp.b2 = b2;
  kp.Wx = Wx; kp.Wh = Wh; kp.Wf = Wf; kp.Wi = Wi;
  kp.Wq = Wq; kp.Wk = Wk; kp.Wv = Wv; kp.Wo = Wo;
  kp.out = (float*)d_out;
  kp.xxp = xxp; kp.fip = fip; kp.qkvp = qkvp; kp.wop = wop;
  kp.xxm = xxm; kp.lt = lt; kp.sp = sp; kp.c = c; kp.attb = attb;
  kp.stats = stats; kp.flags = flags; kp.grel = grel;

  // 256 blocks x 256 thr, ~36 KB LDS -> 1 block/CU on 256 CUs, all co-resident
  vecaw_main<<<dim3(NWG), dim3(NTHR), 0, stream>>>(kp);
}

// Round 5
// 21650.711 us; speedup vs baseline: 1.9320x; 1.0422x over previous
//
#include <hip/hip_runtime.h>

#define NB 64
#define NT 256
#define NF 512
#define NU 1024
#define NWG 256
#define NTHR 256
#define SLICE 65536   // 64*1024 floats per partial K-slice

typedef float f32x4 __attribute__((ext_vector_type(4)));

__device__ __forceinline__ float sigm(float x) { return 1.f / (1.f + __expf(-x)); }

// ---- memory ops (protocol validated round 4) --------------------------------
//  * producers: PLAIN stores + release-fence (buffer_wbl2, dirty-only) at barrier
//  * consumers: sc0 sc1 scoped loads (bypass stale L1/L2, read coherence point)
//  * weights & weight-products: plain cached loads (clean lines, never inv'd)
// Inline-asm loads are NOT dependency-tracked: component reads only after vm_wait().
__device__ __forceinline__ f32x4 ld_cg4(const float* p) {
  f32x4 t;
  asm volatile("global_load_dwordx4 %0, %1, off sc0 sc1" : "=&v"(t) : "v"(p));
  return t;
}
__device__ __forceinline__ float ld_cg1(const float* p) {
  float t;
  asm volatile("global_load_dword %0, %1, off sc0 sc1" : "=&v"(t) : "v"(p));
  return t;
}
__device__ __forceinline__ f32x4 ld_nc4(const float* p) {  // cached load (weights/x)
  f32x4 t;
  asm volatile("global_load_dwordx4 %0, %1, off" : "=&v"(t) : "v"(p));
  return t;
}
__device__ __forceinline__ void vm_wait() {
  asm volatile("s_waitcnt vmcnt(0)" ::: "memory");
  __builtin_amdgcn_sched_barrier(0);
}

struct KParams {
  const float *x, *g1, *b1, *g2, *b2;
  const float *Wx, *Wh, *Wf, *Wi, *Wq, *Wk, *Wv, *Wo;
  float *out;
  float *xp, *qkvp, *wop, *attb, *sp, *stats; // stats: [0..63]=sp mean [64..127]=sp rstd
  float *WhWf, *WhWi, *WxWf, *WxWi;           // precomputed weight products
  int *flags, *grel;
};

// ---- grid barrier: producer-release (wbl2, dirty-only) + scoped-load acquire ----
__device__ __forceinline__ void grid_barrier(int* flags, int* grel, int epoch,
                                             int wg, int tid, bool dirty) {
  asm volatile("s_waitcnt vmcnt(0) lgkmcnt(0)" ::: "memory");
  __syncthreads();   // all waves' plain stores are in L2 before tid0's wbl2
  if (wg == 0) {
    if (tid > 0) {
      while (__hip_atomic_load(&flags[tid * 16], __ATOMIC_RELAXED, __HIP_MEMORY_SCOPE_AGENT) < epoch)
        __builtin_amdgcn_s_sleep(1);
    }
    __syncthreads();
    if (tid == 0)
      __builtin_amdgcn_fence(__ATOMIC_RELEASE, "agent");  // wbl2+waitcnt, NO inv
    __syncthreads();
    if (tid < 16)
      __hip_atomic_store(&grel[tid * 16], epoch, __ATOMIC_RELAXED, __HIP_MEMORY_SCOPE_AGENT);
    __syncthreads();
  } else {
    if (tid == 0) {
      if (dirty)
        __builtin_amdgcn_fence(__ATOMIC_RELEASE, "agent");
      __hip_atomic_store(&flags[wg * 16], epoch, __ATOMIC_RELAXED, __HIP_MEMORY_SCOPE_AGENT);
      const int g = wg >> 4;
      while (__hip_atomic_load(&grel[g * 16], __ATOMIC_RELAXED, __HIP_MEMORY_SCOPE_AGENT) < epoch)
        __builtin_amdgcn_s_sleep(1);
    }
    __syncthreads();
  }
}

// ---- one 64x64 output tile over K = nchunks*64, LDS-staged A and W ----
// A-stage modes: 0 = direct rows, cached (x / weight-product A)
//                4 = direct rows, scoped (attb)
//                1 = h on-the-fly (LN1(sp)+sum4(wop), optional out write)
//                3 = LN1(sp)
__device__ __forceinline__ void gemm_tile(
    float* As, float* Wl, const float* smm, const float* smr,
    int mode, const float* A0, size_t a_ld,
    const float* g1, const float* b1, const float* wop,
    float* outw, size_t out_ld,
    const float* __restrict__ W, int n0, int k0, int nchunks,
    float* __restrict__ dst, int tid)
{
  const int cg = tid & 15, rg = tid >> 4;
  const int c0 = cg * 4, r0 = rg * 4;
  float4 acc0 = {0,0,0,0}, acc1 = {0,0,0,0}, acc2 = {0,0,0,0}, acc3 = {0,0,0,0};

  for (int cc = 0; cc < nchunks; ++cc) {
    const int kc = k0 + cc * 64;
    __syncthreads();

    // ---- issue W tile loads (cached) ----
    f32x4 wv[4];
#pragma unroll
    for (int it = 0; it < 4; ++it) {
      int idx = tid + it * 256;
      int kk = idx >> 4, cgs = idx & 15;
      wv[it] = ld_nc4(W + (size_t)(kc + kk) * NU + n0 + cgs * 4);
    }

    // ---- A tile (raw f32x4; components only touched after a vm_wait) ----
    f32x4 v[4];
    if (mode == 0) {
#pragma unroll
      for (int it = 0; it < 4; ++it) {
        int idx = tid + it * 256;
        int r = idx >> 4, k4 = (idx & 15) << 2;
        v[it] = ld_nc4(A0 + (size_t)r * a_ld + kc + k4);
      }
    } else if (mode == 4) {
#pragma unroll
      for (int it = 0; it < 4; ++it) {
        int idx = tid + it * 256;
        int r = idx >> 4, k4 = (idx & 15) << 2;
        v[it] = ld_cg4(A0 + (size_t)r * a_ld + kc + k4);
      }
    } else if (mode == 3) {
      f32x4 av[4];
#pragma unroll
      for (int it = 0; it < 4; ++it) {
        int idx = tid + it * 256;
        int r = idx >> 4, k4 = (idx & 15) << 2;
        av[it] = ld_cg4(A0 + (size_t)r * NU + kc + k4);
      }
      vm_wait();
#pragma unroll
      for (int it = 0; it < 4; ++it) {
        int idx = tid + it * 256;
        int r = idx >> 4, k4 = (idx & 15) << 2;
        int col = kc + k4;
        float m = smm[r], rs = smr[r];
        f32x4 g  = *(const f32x4*)(g1 + col);
        f32x4 be = *(const f32x4*)(b1 + col);
        v[it] = (av[it] - m) * rs * g + be;
      }
    } else {  // mode 1
      if (A0) {
        f32x4 sv[4], w0v[4], w1v[4];
#pragma unroll
        for (int it = 0; it < 4; ++it) {
          int idx = tid + it * 256;
          int r = idx >> 4, k4 = (idx & 15) << 2;
          int col = kc + k4;
          sv[it]  = ld_cg4(A0 + (size_t)r * NU + col);
          w0v[it] = ld_cg4(wop + 0 * SLICE + (size_t)r * NU + col);
          w1v[it] = ld_cg4(wop + 1 * SLICE + (size_t)r * NU + col);
        }
        vm_wait();
        f32x4 pp[4];
#pragma unroll
        for (int it = 0; it < 4; ++it) {
          int idx = tid + it * 256;
          int r = idx >> 4, k4 = (idx & 15) << 2;
          int col = kc + k4;
          float m = smm[r], rs = smr[r];
          f32x4 g  = *(const f32x4*)(g1 + col);
          f32x4 be = *(const f32x4*)(b1 + col);
          pp[it] = (sv[it] - m) * rs * g + be + w0v[it] + w1v[it];
        }
#pragma unroll
        for (int it = 0; it < 4; ++it) {
          int idx = tid + it * 256;
          int r = idx >> 4, k4 = (idx & 15) << 2;
          int col = kc + k4;
          w0v[it] = ld_cg4(wop + 2 * SLICE + (size_t)r * NU + col);
          w1v[it] = ld_cg4(wop + 3 * SLICE + (size_t)r * NU + col);
        }
        vm_wait();
#pragma unroll
        for (int it = 0; it < 4; ++it) {
          int idx = tid + it * 256;
          int r = idx >> 4, k4 = (idx & 15) << 2;
          v[it] = pp[it] + w0v[it] + w1v[it];
          if (outw) *(f32x4*)(outw + (size_t)r * out_ld + kc + k4) = v[it];  // plain store
        }
      } else {
#pragma unroll
        for (int it = 0; it < 4; ++it) v[it] = (f32x4){0.f, 0.f, 0.f, 0.f};
      }
    }

    vm_wait();   // drains wv (and mode-0/4 v); ONLY NOW may their components be read
#pragma unroll
    for (int it = 0; it < 4; ++it) {
      int idx = tid + it * 256;
      int r = idx >> 4, k4 = (idx & 15) << 2;
      *(f32x4*)(&As[r * 68 + k4]) = v[it];
    }
#pragma unroll
    for (int it = 0; it < 4; ++it) {
      int idx = tid + it * 256;
      int kk = idx >> 4, cgs = idx & 15;
      int sw = (((kk >> 2) ^ cgs) & 15) << 2;
      int base = (cgs * 4) * 68 + sw + (kk & 3);
      Wl[base] = wv[it].x; Wl[base + 68] = wv[it].y; Wl[base + 136] = wv[it].z; Wl[base + 204] = wv[it].w;
    }
    __syncthreads();
#pragma unroll
    for (int kk = 0; kk < 64; kk += 4) {
      int sw = ((((kk >> 2) ^ cg) & 15) << 2);
      const float4 w0 = *(const float4*)(&Wl[(c0 + 0) * 68 + sw]);
      const float4 w1 = *(const float4*)(&Wl[(c0 + 1) * 68 + sw]);
      const float4 w2 = *(const float4*)(&Wl[(c0 + 2) * 68 + sw]);
      const float4 w3 = *(const float4*)(&Wl[(c0 + 3) * 68 + sw]);
      const float4 a0 = *(const float4*)(&As[(r0 + 0) * 68 + kk]);
      const float4 a1 = *(const float4*)(&As[(r0 + 1) * 68 + kk]);
      const float4 a2 = *(const float4*)(&As[(r0 + 2) * 68 + kk]);
      const float4 a3 = *(const float4*)(&As[(r0 + 3) * 68 + kk]);
#define DOT4(ac, av) \
      ac.x = fmaf(av.x, w0.x, fmaf(av.y, w0.y, fmaf(av.z, w0.z, fmaf(av.w, w0.w, ac.x)))); \
      ac.y = fmaf(av.x, w1.x, fmaf(av.y, w1.y, fmaf(av.z, w1.z, fmaf(av.w, w1.w, ac.y)))); \
      ac.z = fmaf(av.x, w2.x, fmaf(av.y, w2.y, fmaf(av.z, w2.z, fmaf(av.w, w2.w, ac.z)))); \
      ac.w = fmaf(av.x, w3.x, fmaf(av.y, w3.y, fmaf(av.z, w3.z, fmaf(av.w, w3.w, ac.w))));
      DOT4(acc0, a0) DOT4(acc1, a1) DOT4(acc2, a2) DOT4(acc3, a3)
#undef DOT4
    }
  }
  // plain coalesced stores; flushed to the coherence point by the barrier's wbl2
  *(float4*)(dst + (size_t)(r0 + 0) * NU + n0 + c0) = acc0;
  *(float4*)(dst + (size_t)(r0 + 1) * NU + n0 + c0) = acc1;
  *(float4*)(dst + (size_t)(r0 + 2) * NU + n0 + c0) = acc2;
  *(float4*)(dst + (size_t)(r0 + 3) * NU + n0 + c0) = acc3;
}

// x-part partial jobs for step t (no step dependency): j in [0,96)
__device__ __forceinline__ void run_xjob(const KParams& p, float* As, float* Wl,
                                         int t, int j, int tid) {
  const int out = j >> 5, rest = j & 31;
  const int xs = rest >> 4, nt = rest & 15;
  const float* W = (out == 0) ? p.Wx : (out == 1) ? p.WxWf : p.WxWi;
  gemm_tile(As, Wl, nullptr, nullptr, 0, p.x + (size_t)t * NF, (size_t)NT * NF,
            nullptr, nullptr, nullptr, nullptr, 0,
            W, nt * 64, xs * 256, 4,
            p.xp + (size_t)(out * 6 + 4 + xs) * SLICE, tid);
}

__global__ __launch_bounds__(NTHR, 1) void vecaw_main(KParams p) {
  const int wg = blockIdx.x;
  const int tid = threadIdx.x;

  __shared__ __align__(16) float As[64 * 68];
  __shared__ __align__(16) float Wl[64 * 68];
  __shared__ float smm[64], smr[64], red[16], att_s[64];

  int epoch = 0;
  f32x4 c_reg = {0.f, 0.f, 0.f, 0.f};   // LN2(longterm), carried in registers (wg<64)

  // ===== precompute WhWf, WhWi, WxWf, WxWi (768 tile-jobs, 3 full rounds) =====
  for (int r = 0; r < 3; ++r) {
    int j = r * 256 + wg;
    const float *A0, *W; float *dst; int jj;
    if (j < 256)      { jj = j;       A0 = p.Wh; W = p.Wf; dst = p.WhWf; }
    else if (j < 512) { jj = j - 256; A0 = p.Wh; W = p.Wi; dst = p.WhWi; }
    else if (j < 640) { jj = j - 512; A0 = p.Wx; W = p.Wf; dst = p.WxWf; }
    else              { jj = j - 640; A0 = p.Wx; W = p.Wi; dst = p.WxWi; }
    const int rb = jj >> 4, nt = jj & 15;
    gemm_tile(As, Wl, nullptr, nullptr, 0, A0 + (size_t)rb * 64 * NU, NU,
              nullptr, nullptr, nullptr, nullptr, 0,
              W, nt * 64, 0, 16, dst + (size_t)rb * 64 * NU, tid);
    grid_barrier(p.flags, p.grel, ++epoch, wg, tid, true);
  }
  // x-part partials for t=0
  if (wg < 96) run_xjob(p, As, Wl, 0, wg, tid);
  grid_barrier(p.flags, p.grel, ++epoch, wg, tid, wg < 96);

  for (int t = 0; t < NT; ++t) {

    // ===== P1: h-part partials of xx,fs,is (192 WGs); h on-the-fly; out(t-1) =====
    if (wg < 192) {
      const int out = wg >> 6, idx = wg & 63, nt = idx & 15, ks = idx >> 4;
      if (tid < 64 && t > 0) {
        float m = ld_cg1(p.stats + tid);
        float r = ld_cg1(p.stats + 64 + tid);
        vm_wait();
        smm[tid] = m; smr[tid] = r;
      }
      const float* W = (out == 0) ? p.Wh : (out == 1) ? p.WhWf : p.WhWi;
      float* outw = (out == 0 && nt == 0 && t > 0) ? (p.out + (size_t)(t - 1) * NU) : nullptr;
      gemm_tile(As, Wl, smm, smr, 1, (t > 0) ? p.sp : nullptr, NU,
                p.g1, p.b1, p.wop, outw, (size_t)NT * NU,
                W, nt * 64, ks * 256, 4,
                p.xp + (size_t)(out * 6 + ks) * SLICE, tid);
    }
    grid_barrier(p.flags, p.grel, ++epoch, wg, tid, wg < 192);

    // ===== P2: elementwise + LN stats + c=LN2(lt) in-register (64 WGs) =====
    if (wg < 64) {
      const int b = wg;
      const size_t off = (size_t)b * NU + tid * 4;
      f32x4 a[18];
#pragma unroll
      for (int s = 0; s < 18; ++s) a[s] = ld_cg4(p.xp + (size_t)s * SLICE + off);
      vm_wait();
      f32x4 xx = a[0] + a[1] + a[2] + a[3] + a[4] + a[5];
      f32x4 fs = a[6] + a[7] + a[8] + a[9] + a[10] + a[11];
      f32x4 is = a[12] + a[13] + a[14] + a[15] + a[16] + a[17];
      f32x4 ltq, spq;
#define P2COMP(C) { \
      float xxv = xx.C; \
      float f = sigm(fs.C), i = sigm(is.C); \
      float ltv = f * c_reg.C + i * tanhf(xxv); \
      float sw = xxv * sigm(xxv); \
      float spin = ltv + sw; \
      ltq.C = ltv; spq.C = spin * sigm(spin); }
      P2COMP(x) P2COMP(y) P2COMP(z) P2COMP(w)
#undef P2COMP
      *(f32x4*)(p.sp + off) = spq;   // plain store; wbl2 at barrier flushes
      float s0 = spq.x + spq.y + spq.z + spq.w;
      float s1 = spq.x*spq.x + spq.y*spq.y + spq.z*spq.z + spq.w*spq.w;
      float s2 = ltq.x + ltq.y + ltq.z + ltq.w;
      float s3 = ltq.x*ltq.x + ltq.y*ltq.y + ltq.z*ltq.z + ltq.w*ltq.w;
#pragma unroll
      for (int m = 1; m < 64; m <<= 1) {
        s0 += __shfl_xor(s0, m, 64); s1 += __shfl_xor(s1, m, 64);
        s2 += __shfl_xor(s2, m, 64); s3 += __shfl_xor(s3, m, 64);
      }
      if ((tid & 63) == 0) {
        int wv = tid >> 6;
        red[wv * 4 + 0] = s0; red[wv * 4 + 1] = s1;
        red[wv * 4 + 2] = s2; red[wv * 4 + 3] = s3;
      }
      __syncthreads();
      {
        float S0 = red[0] + red[4] + red[8]  + red[12];
        float S1 = red[1] + red[5] + red[9]  + red[13];
        float S2 = red[2] + red[6] + red[10] + red[14];
        float S3 = red[3] + red[7] + red[11] + red[15];
        float m1 = S0 * (1.f / 1024.f), v1 = S1 * (1.f / 1024.f) - m1 * m1;
        float m2 = S2 * (1.f / 1024.f), v2 = S3 * (1.f / 1024.f) - m2 * m2;
        float rs2 = rsqrtf(v2 + 1e-3f);
        // c = LN2(lt), kept in registers for next step's P2
        f32x4 g2v = *(const f32x4*)(p.g2 + tid * 4);
        f32x4 b2v = *(const f32x4*)(p.b2 + tid * 4);
        c_reg = (ltq - m2) * rs2 * g2v + b2v;
        if (tid == 0) {
          p.stats[b]      = m1;
          p.stats[64 + b] = rsqrtf(v1 + 1e-3f);
        }
      }
    }
    grid_barrier(p.flags, p.grel, ++epoch, wg, tid, wg < 64);

    // ===== P3: q,k,v partials with LN1-on-stage (192 WGs) =====
    if (wg < 192) {
      if (tid < 64) {
        float m = ld_cg1(p.stats + tid);
        float r = ld_cg1(p.stats + 64 + tid);
        vm_wait();
        smm[tid] = m; smr[tid] = r;
      }
      const int mat = wg >> 6, idx = wg & 63, nt = idx & 15, ks = idx >> 4;
      const float* W = (mat == 0) ? p.Wq : (mat == 1) ? p.Wk : p.Wv;
      gemm_tile(As, Wl, smm, smr, 3, p.sp, NU,
                p.g1, p.b1, nullptr, nullptr, 0,
                W, nt * 64, ks * 256, 4, p.qkvp + (size_t)(mat * 4 + ks) * SLICE, tid);
    }
    grid_barrier(p.flags, p.grel, ++epoch, wg, tid, wg < 192);

    // ===== P4: per-batch 8x8 attention (64 WGs) || x-part partials for t+1 (96 WGs) =====
    if (wg < 64) {
      const int b = wg;
      f32x4 q0[3], q1[3], q2[3], q3[3];
#pragma unroll
      for (int it = 0; it < 3; ++it) {
        int e4 = (tid + it * 256) * 4;
        int m = e4 >> 10, d = e4 & 1023;
        const float* base = p.qkvp + (size_t)(m * 4) * SLICE + (size_t)b * NU + d;
        q0[it] = ld_cg4(base);
        q1[it] = ld_cg4(base + SLICE);
        q2[it] = ld_cg4(base + 2 * SLICE);
        q3[it] = ld_cg4(base + 3 * SLICE);
      }
      vm_wait();
#pragma unroll
      for (int it = 0; it < 3; ++it) {
        int e4 = (tid + it * 256) * 4;
        f32x4 s = q0[it] + q1[it] + q2[it] + q3[it];
        *(f32x4*)(&As[e4]) = s;
      }
      __syncthreads();
      if (tid < 64) {
        int h = tid >> 3, g = tid & 7;
        float s = 0.f;
#pragma unroll 8
        for (int d = 0; d < 128; ++d) s = fmaf(As[h * 128 + d], As[1024 + g * 128 + d], s);
        att_s[tid] = s * 0.08838834764831845f;   // 1/sqrt(128)
      }
      __syncthreads();
      if (tid < 8) {
        float mx = -1e30f;
#pragma unroll
        for (int g = 0; g < 8; ++g) mx = fmaxf(mx, att_s[tid * 8 + g]);
        float e8[8], sum = 0.f;
#pragma unroll
        for (int g = 0; g < 8; ++g) { e8[g] = __expf(att_s[tid * 8 + g] - mx); sum += e8[g]; }
        float inv = 1.f / sum;
#pragma unroll
        for (int g = 0; g < 8; ++g) att_s[tid * 8 + g] = e8[g] * inv;
      }
      __syncthreads();
      {
        int idx4 = tid * 4;
        int h = idx4 >> 7, d = idx4 & 127;
        f32x4 a = {0.f, 0.f, 0.f, 0.f};
#pragma unroll
        for (int g = 0; g < 8; ++g) {
          float w = att_s[h * 8 + g];
          a += w * (*(const f32x4*)(&As[2048 + g * 128 + d]));
        }
        *(f32x4*)(p.attb + (size_t)b * NU + idx4) = a;   // plain store
      }
    } else if (wg < 160 && t + 1 < NT) {
      run_xjob(p, As, Wl, t + 1, wg - 64, tid);
    }
    grid_barrier(p.flags, p.grel, ++epoch, wg, tid, wg < 160);

    // ===== P5: wo partials (64 WGs, K=256) =====
    if (wg < 64) {
      const int nt = wg & 15, ks = wg >> 4;
      gemm_tile(As, Wl, nullptr, nullptr, 4, p.attb, NU,
                nullptr, nullptr, nullptr, nullptr, 0,
                p.Wo, nt * 64, ks * 256, 4, p.wop + (size_t)ks * SLICE, tid);
    }
    grid_barrier(p.flags, p.grel, ++epoch, wg, tid, wg < 64);
  }

  // ===== final epilogue: out(255) = LN1(sp) + sum(wop) =====
  if (wg < 64) {
    const int b = wg;
    const int u4 = tid * 4;
    const size_t off = (size_t)b * NU + u4;
    float m  = ld_cg1(p.stats + b);
    float rs = ld_cg1(p.stats + 64 + b);
    f32x4 s4 = ld_cg4(p.sp + off);
    f32x4 w0 = ld_cg4(p.wop + off);
    f32x4 w1 = ld_cg4(p.wop + SLICE + off);
    f32x4 w2 = ld_cg4(p.wop + 2 * SLICE + off);
    f32x4 w3 = ld_cg4(p.wop + 3 * SLICE + off);
    vm_wait();
    f32x4 g  = *(const f32x4*)(p.g1 + u4);
    f32x4 be = *(const f32x4*)(p.b1 + u4);
    f32x4 o = (s4 - m) * rs * g + be + w0 + w1 + w2 + w3;
    *(f32x4*)(p.out + ((size_t)b * NT + 255) * NU + u4) = o;
  }
}

extern "C" void kernel_launch(void* const* d_in, const int* in_sizes, int n_in,
                              void* d_out, int out_size, void* d_ws, size_t ws_size,
                              hipStream_t stream) {
  (void)in_sizes; (void)n_in; (void)out_size; (void)ws_size;
  const float* x  = (const float*)d_in[0];
  const float* Wx = (const float*)d_in[1];
  const float* Wh = (const float*)d_in[2];
  const float* Wq = (const float*)d_in[3];
  const float* Wk = (const float*)d_in[4];
  const float* Wv = (const float*)d_in[5];
  const float* Wo = (const float*)d_in[6];
  const float* Wf = (const float*)d_in[7];
  const float* Wi = (const float*)d_in[8];
  const float* g1 = (const float*)d_in[9];
  const float* b1 = (const float*)d_in[10];
  const float* g2 = (const float*)d_in[11];
  const float* b2 = (const float*)d_in[12];

  char* pp = (char*)d_ws;
  auto take = [&](size_t bytes) { char* r = pp; pp += (bytes + 255) & ~(size_t)255; return r; };
  // --- memset region: flags | grel | stats ---
  int*   flags = (int*)take(256 * 16 * 4);     // one 64B line per WG
  int*   grel  = (int*)take(16 * 16 * 4);      // one 64B line per 16-WG group
  float* stats = (float*)take(256 * 4);        // [mean_sp | rstd_sp] x 64
  size_t zbytes = (size_t)(pp - (char*)d_ws);
  // --- rest (fully overwritten before read) ---
  float* xp    = (float*)take((size_t)18 * SLICE * 4);  // [out=xx,fs,is][6 k-slices]
  float* qkvp  = (float*)take((size_t)12 * SLICE * 4);
  float* wop   = (float*)take((size_t)4 * SLICE * 4);
  float* attb  = (float*)take((size_t)SLICE * 4);
  float* sp    = (float*)take((size_t)SLICE * 4);
  float* WhWf  = (float*)take((size_t)16 * SLICE * 4);  // 1024x1024
  float* WhWi  = (float*)take((size_t)16 * SLICE * 4);
  float* WxWf  = (float*)take((size_t)8 * SLICE * 4);   // 512x1024
  float* WxWi  = (float*)take((size_t)8 * SLICE * 4);

  hipMemsetAsync(d_ws, 0, zbytes, stream);

  KParams kp;
  kp.x = x; kp.g1 = g1; kp.b1 = b1; kp.g2 = g2; kp.b2 = b2;
  kp.Wx = Wx; kp.Wh = Wh; kp.Wf = Wf; kp.Wi = Wi;
  kp.Wq = Wq; kp.Wk = Wk; kp.Wv = Wv; kp.Wo = Wo;
  kp.out = (float*)d_out;
  kp.xp = xp; kp.qkvp = qkvp; kp.wop = wop; kp.attb = attb; kp.sp = sp;
  kp.stats = stats;
  kp.WhWf = WhWf; kp.WhWi = WhWi; kp.WxWf = WxWf; kp.WxWi = WxWi;
  kp.flags = flags; kp.grel = grel;

  // 256 blocks x 256 thr, ~36 KB LDS -> 1 block/CU on 256 CUs, all co-resident
  vecaw_main<<<dim3(NWG), dim3(NTHR), 0, stream>>>(kp);
}

// Round 6
// 20804.506 us; speedup vs baseline: 2.0106x; 1.0407x over previous
//
#include <hip/hip_runtime.h>

#define NB 64
#define NT 256
#define NF 512
#define NU 1024
#define NWG 256
#define NTHR 256
#define SLICE 65536   // 64*1024 floats per partial K-slice

typedef float f32x4 __attribute__((ext_vector_type(4)));

__device__ __forceinline__ float sigm(float x) { return 1.f / (1.f + __expf(-x)); }

// ---- memory ops (protocol validated round 4/5) ------------------------------
//  * producers: PLAIN stores + release-fence (buffer_wbl2, dirty-only) at barrier
//  * consumers: sc0 sc1 scoped loads (bypass stale L1/L2, read coherence point)
//  * weights & weight-products: plain cached loads (clean lines, never inv'd)
// Inline-asm loads are NOT dependency-tracked: component reads only after vm_wait().
__device__ __forceinline__ f32x4 ld_cg4(const float* p) {
  f32x4 t;
  asm volatile("global_load_dwordx4 %0, %1, off sc0 sc1" : "=&v"(t) : "v"(p));
  return t;
}
__device__ __forceinline__ float ld_cg1(const float* p) {
  float t;
  asm volatile("global_load_dword %0, %1, off sc0 sc1" : "=&v"(t) : "v"(p));
  return t;
}
__device__ __forceinline__ f32x4 ld_nc4(const float* p) {  // cached load (weights/x)
  f32x4 t;
  asm volatile("global_load_dwordx4 %0, %1, off" : "=&v"(t) : "v"(p));
  return t;
}
__device__ __forceinline__ void vm_wait() {
  asm volatile("s_waitcnt vmcnt(0)" ::: "memory");
  __builtin_amdgcn_sched_barrier(0);
}

struct KParams {
  const float *x, *g1, *b1, *g2, *b2;
  const float *Wx, *Wh, *Wf, *Wi, *Wq, *Wk, *Wv, *Wo;
  float *out;
  float *xp;     // 24 slices: [o=xx,fs,is][ Gsp ks0-3 | Gattb ks0-3 ]
  float *xjp;    // 12 slices: [par][o][xs]  (x-part partials, parity = consuming t&1)
  float *qkvp;   // 12 slices
  float *wop;    // 4 slices (attb@Wo partials for out)
  float *attb;   // 1 slice
  float *sp;     // 2 slices (parity)
  float *stats;  // [par][0..63]=sp mean  [par][64..127]=sp rstd
  float *WhWf, *WhWi, *WxWf, *WxWi, *WoWh, *WoWhWf, *WoWhWi;
  int *flags, *grel;
};

// ---- grid barrier: producer-release (wbl2, dirty-only) + scoped-load acquire ----
__device__ __forceinline__ void grid_barrier(int* flags, int* grel, int epoch,
                                             int wg, int tid, bool dirty) {
  asm volatile("s_waitcnt vmcnt(0) lgkmcnt(0)" ::: "memory");
  __syncthreads();   // all waves' plain stores are in L2 before tid0's wbl2
  if (wg == 0) {
    if (tid > 0) {
      while (__hip_atomic_load(&flags[tid * 16], __ATOMIC_RELAXED, __HIP_MEMORY_SCOPE_AGENT) < epoch)
        __builtin_amdgcn_s_sleep(1);
    }
    __syncthreads();
    if (tid == 0)
      __builtin_amdgcn_fence(__ATOMIC_RELEASE, "agent");  // wbl2+waitcnt, NO inv
    __syncthreads();
    if (tid < 16)
      __hip_atomic_store(&grel[tid * 16], epoch, __ATOMIC_RELAXED, __HIP_MEMORY_SCOPE_AGENT);
    __syncthreads();
  } else {
    if (tid == 0) {
      if (dirty)
        __builtin_amdgcn_fence(__ATOMIC_RELEASE, "agent");
      __hip_atomic_store(&flags[wg * 16], epoch, __ATOMIC_RELAXED, __HIP_MEMORY_SCOPE_AGENT);
      const int g = wg >> 4;
      while (__hip_atomic_load(&grel[g * 16], __ATOMIC_RELAXED, __HIP_MEMORY_SCOPE_AGENT) < epoch)
        __builtin_amdgcn_s_sleep(1);
    }
    __syncthreads();
  }
}

// ---- one 64x64 output tile over K = nchunks*64, LDS-staged A and W ----
// A-stage modes: 0 = direct rows, cached (x / weight operands)
//                3 = LN1(sp) on stage, scoped
//                4 = direct rows, scoped (attb)
__device__ __forceinline__ void gemm_tile(
    float* As, float* Wl, const float* smm, const float* smr,
    int mode, const float* A0, size_t a_ld,
    const float* g1, const float* b1,
    const float* __restrict__ W, int n0, int k0, int nchunks,
    float* __restrict__ dst, int tid)
{
  const int cg = tid & 15, rg = tid >> 4;
  const int c0 = cg * 4, r0 = rg * 4;
  float4 acc0 = {0,0,0,0}, acc1 = {0,0,0,0}, acc2 = {0,0,0,0}, acc3 = {0,0,0,0};

  for (int cc = 0; cc < nchunks; ++cc) {
    const int kc = k0 + cc * 64;
    __syncthreads();

    // ---- issue W tile loads (cached) ----
    f32x4 wv[4];
#pragma unroll
    for (int it = 0; it < 4; ++it) {
      int idx = tid + it * 256;
      int kk = idx >> 4, cgs = idx & 15;
      wv[it] = ld_nc4(W + (size_t)(kc + kk) * NU + n0 + cgs * 4);
    }

    // ---- A tile (raw f32x4; components only touched after a vm_wait) ----
    f32x4 v[4];
    if (mode == 0) {
#pragma unroll
      for (int it = 0; it < 4; ++it) {
        int idx = tid + it * 256;
        int r = idx >> 4, k4 = (idx & 15) << 2;
        v[it] = ld_nc4(A0 + (size_t)r * a_ld + kc + k4);
      }
    } else if (mode == 4) {
#pragma unroll
      for (int it = 0; it < 4; ++it) {
        int idx = tid + it * 256;
        int r = idx >> 4, k4 = (idx & 15) << 2;
        v[it] = ld_cg4(A0 + (size_t)r * a_ld + kc + k4);
      }
    } else {  // mode 3: LN1(sp)
      f32x4 av[4];
#pragma unroll
      for (int it = 0; it < 4; ++it) {
        int idx = tid + it * 256;
        int r = idx >> 4, k4 = (idx & 15) << 2;
        av[it] = ld_cg4(A0 + (size_t)r * NU + kc + k4);
      }
      vm_wait();
#pragma unroll
      for (int it = 0; it < 4; ++it) {
        int idx = tid + it * 256;
        int r = idx >> 4, k4 = (idx & 15) << 2;
        int col = kc + k4;
        float m = smm[r], rs = smr[r];
        f32x4 g  = *(const f32x4*)(g1 + col);
        f32x4 be = *(const f32x4*)(b1 + col);
        v[it] = (av[it] - m) * rs * g + be;
      }
    }

    vm_wait();   // drains wv (and mode-0/4 v); ONLY NOW may their components be read
#pragma unroll
    for (int it = 0; it < 4; ++it) {
      int idx = tid + it * 256;
      int r = idx >> 4, k4 = (idx & 15) << 2;
      *(f32x4*)(&As[r * 68 + k4]) = v[it];
    }
#pragma unroll
    for (int it = 0; it < 4; ++it) {
      int idx = tid + it * 256;
      int kk = idx >> 4, cgs = idx & 15;
      int sw = (((kk >> 2) ^ cgs) & 15) << 2;
      int base = (cgs * 4) * 68 + sw + (kk & 3);
      Wl[base] = wv[it].x; Wl[base + 68] = wv[it].y; Wl[base + 136] = wv[it].z; Wl[base + 204] = wv[it].w;
    }
    __syncthreads();
#pragma unroll
    for (int kk = 0; kk < 64; kk += 4) {
      int sw = ((((kk >> 2) ^ cg) & 15) << 2);
      const float4 w0 = *(const float4*)(&Wl[(c0 + 0) * 68 + sw]);
      const float4 w1 = *(const float4*)(&Wl[(c0 + 1) * 68 + sw]);
      const float4 w2 = *(const float4*)(&Wl[(c0 + 2) * 68 + sw]);
      const float4 w3 = *(const float4*)(&Wl[(c0 + 3) * 68 + sw]);
      const float4 a0 = *(const float4*)(&As[(r0 + 0) * 68 + kk]);
      const float4 a1 = *(const float4*)(&As[(r0 + 1) * 68 + kk]);
      const float4 a2 = *(const float4*)(&As[(r0 + 2) * 68 + kk]);
      const float4 a3 = *(const float4*)(&As[(r0 + 3) * 68 + kk]);
#define DOT4(ac, av) \
      ac.x = fmaf(av.x, w0.x, fmaf(av.y, w0.y, fmaf(av.z, w0.z, fmaf(av.w, w0.w, ac.x)))); \
      ac.y = fmaf(av.x, w1.x, fmaf(av.y, w1.y, fmaf(av.z, w1.z, fmaf(av.w, w1.w, ac.y)))); \
      ac.z = fmaf(av.x, w2.x, fmaf(av.y, w2.y, fmaf(av.z, w2.z, fmaf(av.w, w2.w, ac.z)))); \
      ac.w = fmaf(av.x, w3.x, fmaf(av.y, w3.y, fmaf(av.z, w3.z, fmaf(av.w, w3.w, ac.w))));
      DOT4(acc0, a0) DOT4(acc1, a1) DOT4(acc2, a2) DOT4(acc3, a3)
#undef DOT4
    }
  }
  // plain coalesced stores; flushed to the coherence point by the barrier's wbl2
  *(float4*)(dst + (size_t)(r0 + 0) * NU + n0 + c0) = acc0;
  *(float4*)(dst + (size_t)(r0 + 1) * NU + n0 + c0) = acc1;
  *(float4*)(dst + (size_t)(r0 + 2) * NU + n0 + c0) = acc2;
  *(float4*)(dst + (size_t)(r0 + 3) * NU + n0 + c0) = acc3;
}

// x-part partial jobs for step t (no step dependency): j in [0,96)
__device__ __forceinline__ void run_xjob(const KParams& p, float* As, float* Wl,
                                         int t, int j, int tid) {
  const int o = j >> 5, rest = j & 31;
  const int xs = rest >> 4, nt = rest & 15;
  const float* W = (o == 0) ? p.Wx : (o == 1) ? p.WxWf : p.WxWi;
  float* dst = p.xjp + ((size_t)(t & 1) * 6 + o * 2 + xs) * SLICE;
  gemm_tile(As, Wl, nullptr, nullptr, 0, p.x + (size_t)t * NF, (size_t)NT * NF,
            nullptr, nullptr, W, nt * 64, xs * 256, 4, dst, tid);
}

__global__ __launch_bounds__(NTHR, 1) void vecaw_main(KParams p) {
  const int wg = blockIdx.x;
  const int tid = threadIdx.x;

  __shared__ __align__(16) float As[64 * 68];
  __shared__ __align__(16) float Wl[64 * 68];
  __shared__ float smm[64], smr[64], red[16], att_s[64];

  int epoch = 0;
  f32x4 c_reg = {0.f, 0.f, 0.f, 0.f};   // LN2(longterm), carried in registers (wg<64)

  // ===== precompute set 1: WhWf, WhWi, WxWf, WxWi (768 jobs, 3 rounds) =====
  for (int r = 0; r < 3; ++r) {
    int j = r * 256 + wg;
    const float *A0, *W; float *dst; int jj;
    if (j < 256)      { jj = j;       A0 = p.Wh; W = p.Wf; dst = p.WhWf; }
    else if (j < 512) { jj = j - 256; A0 = p.Wh; W = p.Wi; dst = p.WhWi; }
    else if (j < 640) { jj = j - 512; A0 = p.Wx; W = p.Wf; dst = p.WxWf; }
    else              { jj = j - 640; A0 = p.Wx; W = p.Wi; dst = p.WxWi; }
    const int rb = jj >> 4, nt = jj & 15;
    gemm_tile(As, Wl, nullptr, nullptr, 0, A0 + (size_t)rb * 64 * NU, NU,
              nullptr, nullptr, W, nt * 64, 0, 16, dst + (size_t)rb * 64 * NU, tid);
    grid_barrier(p.flags, p.grel, ++epoch, wg, tid, true);
  }
  // ===== precompute set 2: WoWh, WoWhWf, WoWhWi (768 jobs, 3 rounds) =====
  for (int r = 0; r < 3; ++r) {
    int j = r * 256 + wg;
    const float *W; float *dst; int jj;
    if (j < 256)      { jj = j;       W = p.Wh;   dst = p.WoWh;   }
    else if (j < 512) { jj = j - 256; W = p.WhWf; dst = p.WoWhWf; }
    else              { jj = j - 512; W = p.WhWi; dst = p.WoWhWi; }
    const int rb = jj >> 4, nt = jj & 15;
    gemm_tile(As, Wl, nullptr, nullptr, 0, p.Wo + (size_t)rb * 64 * NU, NU,
              nullptr, nullptr, W, nt * 64, 0, 16, dst + (size_t)rb * 64 * NU, tid);
    grid_barrier(p.flags, p.grel, ++epoch, wg, tid, true);
  }
  // x-part partials for t=0 (parity 0)
  if (wg < 96) run_xjob(p, As, Wl, 0, wg, tid);
  grid_barrier(p.flags, p.grel, ++epoch, wg, tid, wg < 96);

  for (int t = 0; t < NT; ++t) {
    const int par = t & 1;

    // ===== PhA: elementwise+stats+c (64 WGs)  ||  xjobs(t+1) (96 WGs) =====
    if (wg < 64) {
      const int b = wg;
      const size_t off = (size_t)b * NU + tid * 4;
      f32x4 a0[10], a1[10], a2[10];
#pragma unroll
      for (int s = 0; s < 8; ++s) {
        a0[s] = ld_cg4(p.xp + (size_t)(0 * 8 + s) * SLICE + off);
        a1[s] = ld_cg4(p.xp + (size_t)(1 * 8 + s) * SLICE + off);
        a2[s] = ld_cg4(p.xp + (size_t)(2 * 8 + s) * SLICE + off);
      }
#pragma unroll
      for (int s = 0; s < 2; ++s) {
        a0[8 + s] = ld_cg4(p.xjp + ((size_t)par * 6 + 0 * 2 + s) * SLICE + off);
        a1[8 + s] = ld_cg4(p.xjp + ((size_t)par * 6 + 1 * 2 + s) * SLICE + off);
        a2[8 + s] = ld_cg4(p.xjp + ((size_t)par * 6 + 2 * 2 + s) * SLICE + off);
      }
      vm_wait();
      f32x4 xx = a0[0], fs = a1[0], is = a2[0];
#pragma unroll
      for (int s = 1; s < 10; ++s) { xx += a0[s]; fs += a1[s]; is += a2[s]; }
      f32x4 ltq, spq;
#define PACOMP(C) { \
      float xxv = xx.C; \
      float f = sigm(fs.C), i = sigm(is.C); \
      float ltv = f * c_reg.C + i * tanhf(xxv); \
      float sw = xxv * sigm(xxv); \
      float spin = ltv + sw; \
      ltq.C = ltv; spq.C = spin * sigm(spin); }
      PACOMP(x) PACOMP(y) PACOMP(z) PACOMP(w)
#undef PACOMP
      *(f32x4*)(p.sp + (size_t)par * SLICE + off) = spq;  // plain; wbl2 flushes
      float s0 = spq.x + spq.y + spq.z + spq.w;
      float s1 = spq.x*spq.x + spq.y*spq.y + spq.z*spq.z + spq.w*spq.w;
      float s2 = ltq.x + ltq.y + ltq.z + ltq.w;
      float s3 = ltq.x*ltq.x + ltq.y*ltq.y + ltq.z*ltq.z + ltq.w*ltq.w;
#pragma unroll
      for (int m = 1; m < 64; m <<= 1) {
        s0 += __shfl_xor(s0, m, 64); s1 += __shfl_xor(s1, m, 64);
        s2 += __shfl_xor(s2, m, 64); s3 += __shfl_xor(s3, m, 64);
      }
      if ((tid & 63) == 0) {
        int wv = tid >> 6;
        red[wv * 4 + 0] = s0; red[wv * 4 + 1] = s1;
        red[wv * 4 + 2] = s2; red[wv * 4 + 3] = s3;
      }
      __syncthreads();
      {
        float S0 = red[0] + red[4] + red[8]  + red[12];
        float S1 = red[1] + red[5] + red[9]  + red[13];
        float S2 = red[2] + red[6] + red[10] + red[14];
        float S3 = red[3] + red[7] + red[11] + red[15];
        float m1 = S0 * (1.f / 1024.f), v1 = S1 * (1.f / 1024.f) - m1 * m1;
        float m2 = S2 * (1.f / 1024.f), v2 = S3 * (1.f / 1024.f) - m2 * m2;
        float rs2 = rsqrtf(v2 + 1e-3f);
        f32x4 g2v = *(const f32x4*)(p.g2 + tid * 4);
        f32x4 b2v = *(const f32x4*)(p.b2 + tid * 4);
        c_reg = (ltq - m2) * rs2 * g2v + b2v;   // c = LN2(lt), in registers
        if (tid == 0) {
          p.stats[par * 128 + b]      = m1;
          p.stats[par * 128 + 64 + b] = rsqrtf(v1 + 1e-3f);
        }
      }
    } else if (wg < 160 && t + 1 < NT) {
      run_xjob(p, As, Wl, t + 1, wg - 64, tid);
    }
    grid_barrier(p.flags, p.grel, ++epoch, wg, tid, wg < 160);

    // ===== PhB: qkv (192 WGs)  ||  out(t-1) finalize (64 WGs) =====
    if (wg < 192) {
      if (tid < 64) {
        float m = ld_cg1(p.stats + par * 128 + tid);
        float r = ld_cg1(p.stats + par * 128 + 64 + tid);
        vm_wait();
        smm[tid] = m; smr[tid] = r;
      }
      const int mat = wg >> 6, idx = wg & 63, nt = idx & 15, ks = idx >> 4;
      const float* W = (mat == 0) ? p.Wq : (mat == 1) ? p.Wk : p.Wv;
      gemm_tile(As, Wl, smm, smr, 3, p.sp + (size_t)par * SLICE, NU,
                p.g1, p.b1, W, nt * 64, ks * 256, 4,
                p.qkvp + (size_t)(mat * 4 + ks) * SLICE, tid);
    } else if (t > 0) {
      const int b = wg - 192, pold = (t - 1) & 1;
      const int u4 = tid * 4;
      const size_t off = (size_t)b * NU + u4;
      float m  = ld_cg1(p.stats + pold * 128 + b);
      float rs = ld_cg1(p.stats + pold * 128 + 64 + b);
      f32x4 s4 = ld_cg4(p.sp + (size_t)pold * SLICE + off);
      f32x4 w0 = ld_cg4(p.wop + off);
      f32x4 w1 = ld_cg4(p.wop + SLICE + off);
      f32x4 w2 = ld_cg4(p.wop + 2 * SLICE + off);
      f32x4 w3 = ld_cg4(p.wop + 3 * SLICE + off);
      vm_wait();
      f32x4 g  = *(const f32x4*)(p.g1 + u4);
      f32x4 be = *(const f32x4*)(p.b1 + u4);
      f32x4 o = (s4 - m) * rs * g + be + w0 + w1 + w2 + w3;
      *(f32x4*)(p.out + ((size_t)b * NT + (t - 1)) * NU + u4) = o;  // plain; kernel-end flush
    }
    grid_barrier(p.flags, p.grel, ++epoch, wg, tid, wg < 192);

    // ===== PhC: attention (64 WGs)  ||  Gsp(t+1) = LN1(sp)@WhFam (192 WGs) =====
    if (wg < 64) {
      const int b = wg;
      f32x4 q0[3], q1[3], q2[3], q3[3];
#pragma unroll
      for (int it = 0; it < 3; ++it) {
        int e4 = (tid + it * 256) * 4;
        int m = e4 >> 10, d = e4 & 1023;
        const float* base = p.qkvp + (size_t)(m * 4) * SLICE + (size_t)b * NU + d;
        q0[it] = ld_cg4(base);
        q1[it] = ld_cg4(base + SLICE);
        q2[it] = ld_cg4(base + 2 * SLICE);
        q3[it] = ld_cg4(base + 3 * SLICE);
      }
      vm_wait();
#pragma unroll
      for (int it = 0; it < 3; ++it) {
        int e4 = (tid + it * 256) * 4;
        f32x4 s = q0[it] + q1[it] + q2[it] + q3[it];
        *(f32x4*)(&As[e4]) = s;
      }
      __syncthreads();
      if (tid < 64) {
        int h = tid >> 3, g = tid & 7;
        float s = 0.f;
#pragma unroll 8
        for (int d = 0; d < 128; ++d) s = fmaf(As[h * 128 + d], As[1024 + g * 128 + d], s);
        att_s[tid] = s * 0.08838834764831845f;   // 1/sqrt(128)
      }
      __syncthreads();
      if (tid < 8) {
        float mx = -1e30f;
#pragma unroll
        for (int g = 0; g < 8; ++g) mx = fmaxf(mx, att_s[tid * 8 + g]);
        float e8[8], sum = 0.f;
#pragma unroll
        for (int g = 0; g < 8; ++g) { e8[g] = __expf(att_s[tid * 8 + g] - mx); sum += e8[g]; }
        float inv = 1.f / sum;
#pragma unroll
        for (int g = 0; g < 8; ++g) att_s[tid * 8 + g] = e8[g] * inv;
      }
      __syncthreads();
      {
        int idx4 = tid * 4;
        int h = idx4 >> 7, d = idx4 & 127;
        f32x4 a = {0.f, 0.f, 0.f, 0.f};
#pragma unroll
        for (int g = 0; g < 8; ++g) {
          float w = att_s[h * 8 + g];
          a += w * (*(const f32x4*)(&As[2048 + g * 128 + d]));
        }
        *(f32x4*)(p.attb + (size_t)b * NU + idx4) = a;   // plain store
      }
    } else if (t + 1 < NT) {
      if (tid < 64) {
        float m = ld_cg1(p.stats + par * 128 + tid);
        float r = ld_cg1(p.stats + par * 128 + 64 + tid);
        vm_wait();
        smm[tid] = m; smr[tid] = r;
      }
      const int j = wg - 64, o = j >> 6, idx = j & 63, nt = idx & 15, ks = idx >> 4;
      const float* W = (o == 0) ? p.Wh : (o == 1) ? p.WhWf : p.WhWi;
      gemm_tile(As, Wl, smm, smr, 3, p.sp + (size_t)par * SLICE, NU,
                p.g1, p.b1, W, nt * 64, ks * 256, 4,
                p.xp + (size_t)(o * 8 + ks) * SLICE, tid);
    }
    grid_barrier(p.flags, p.grel, ++epoch, wg, tid, (wg < 64) || (t + 1 < NT));

    // ===== PhD: Gattb(t+1) = attb@WoWhFam (192 WGs)  ||  woP = attb@Wo (64 WGs) =====
    if (wg < 192) {
      if (t + 1 < NT) {
        const int o = wg >> 6, idx = wg & 63, nt = idx & 15, ks = idx >> 4;
        const float* W = (o == 0) ? p.WoWh : (o == 1) ? p.WoWhWf : p.WoWhWi;
        gemm_tile(As, Wl, nullptr, nullptr, 4, p.attb, NU,
                  nullptr, nullptr, W, nt * 64, ks * 256, 4,
                  p.xp + (size_t)(o * 8 + 4 + ks) * SLICE, tid);
      }
    } else {
      const int idx = wg - 192, nt = idx & 15, ks = idx >> 4;
      gemm_tile(As, Wl, nullptr, nullptr, 4, p.attb, NU,
                nullptr, nullptr, p.Wo, nt * 64, ks * 256, 4,
                p.wop + (size_t)ks * SLICE, tid);
    }
    grid_barrier(p.flags, p.grel, ++epoch, wg, tid, (wg >= 192) || (t + 1 < NT));
  }

  // ===== post-loop: finalize out(255) =====
  if (wg >= 192) {
    const int b = wg - 192;
    const int u4 = tid * 4;
    const size_t off = (size_t)b * NU + u4;
    float m  = ld_cg1(p.stats + 128 + b);          // par(255)=1
    float rs = ld_cg1(p.stats + 128 + 64 + b);
    f32x4 s4 = ld_cg4(p.sp + SLICE + off);
    f32x4 w0 = ld_cg4(p.wop + off);
    f32x4 w1 = ld_cg4(p.wop + SLICE + off);
    f32x4 w2 = ld_cg4(p.wop + 2 * SLICE + off);
    f32x4 w3 = ld_cg4(p.wop + 3 * SLICE + off);
    vm_wait();
    f32x4 g  = *(const f32x4*)(p.g1 + u4);
    f32x4 be = *(const f32x4*)(p.b1 + u4);
    f32x4 o = (s4 - m) * rs * g + be + w0 + w1 + w2 + w3;
    *(f32x4*)(p.out + ((size_t)b * NT + 255) * NU + u4) = o;
  }
}

extern "C" void kernel_launch(void* const* d_in, const int* in_sizes, int n_in,
                              void* d_out, int out_size, void* d_ws, size_t ws_size,
                              hipStream_t stream) {
  (void)in_sizes; (void)n_in; (void)out_size; (void)ws_size;
  const float* x  = (const float*)d_in[0];
  const float* Wx = (const float*)d_in[1];
  const float* Wh = (const float*)d_in[2];
  const float* Wq = (const float*)d_in[3];
  const float* Wk = (const float*)d_in[4];
  const float* Wv = (const float*)d_in[5];
  const float* Wo = (const float*)d_in[6];
  const float* Wf = (const float*)d_in[7];
  const float* Wi = (const float*)d_in[8];
  const float* g1 = (const float*)d_in[9];
  const float* b1 = (const float*)d_in[10];
  const float* g2 = (const float*)d_in[11];
  const float* b2 = (const float*)d_in[12];

  char* pp = (char*)d_ws;
  auto take = [&](size_t bytes) { char* r = pp; pp += (bytes + 255) & ~(size_t)255; return r; };
  // --- memset region: flags | grel | stats | xp (G-slices must start zero) ---
  int*   flags = (int*)take(256 * 16 * 4);
  int*   grel  = (int*)take(16 * 16 * 4);
  float* stats = (float*)take(2 * 128 * 4);
  float* xp    = (float*)take((size_t)24 * SLICE * 4);
  size_t zbytes = (size_t)(pp - (char*)d_ws);
  // --- rest (fully overwritten before read) ---
  float* xjp    = (float*)take((size_t)12 * SLICE * 4);
  float* qkvp   = (float*)take((size_t)12 * SLICE * 4);
  float* wop    = (float*)take((size_t)4 * SLICE * 4);
  float* attb   = (float*)take((size_t)SLICE * 4);
  float* sp     = (float*)take((size_t)2 * SLICE * 4);
  float* WhWf   = (float*)take((size_t)16 * SLICE * 4);
  float* WhWi   = (float*)take((size_t)16 * SLICE * 4);
  float* WxWf   = (float*)take((size_t)8 * SLICE * 4);
  float* WxWi   = (float*)take((size_t)8 * SLICE * 4);
  float* WoWh   = (float*)take((size_t)16 * SLICE * 4);
  float* WoWhWf = (float*)take((size_t)16 * SLICE * 4);
  float* WoWhWi = (float*)take((size_t)16 * SLICE * 4);

  hipMemsetAsync(d_ws, 0, zbytes, stream);

  KParams kp;
  kp.x = x; kp.g1 = g1; kp.b1 = b1; kp.g2 = g2; kp.b2 = b2;
  kp.Wx = Wx; kp.Wh = Wh; kp.Wf = Wf; kp.Wi = Wi;
  kp.Wq = Wq; kp.Wk = Wk; kp.Wv = Wv; kp.Wo = Wo;
  kp.out = (float*)d_out;
  kp.xp = xp; kp.xjp = xjp; kp.qkvp = qkvp; kp.wop = wop;
  kp.attb = attb; kp.sp = sp; kp.stats = stats;
  kp.WhWf = WhWf; kp.WhWi = WhWi; kp.WxWf = WxWf; kp.WxWi = WxWi;
  kp.WoWh = WoWh; kp.WoWhWf = WoWhWf; kp.WoWhWi = WoWhWi;
  kp.flags = flags; kp.grel = grel;

  // 256 blocks x 256 thr, ~36 KB LDS -> 1 block/CU on 256 CUs, all co-resident
  vecaw_main<<<dim3(NWG), dim3(NTHR), 0, stream>>>(kp);
}